// Round 2
// baseline (444.974 us; speedup 1.0000x reference)
//
#include <hip/hip_runtime.h>
#include <math.h>

#define BB 32
#define HH 512
#define WW 512
#define NB 4096                      // 64*64 blocks per image
#define QD 25165824                  // 32*3*4096*64  (qdct elements)
#define PP 16777216                  // 32*512*512*2  (enc_qf elements)
#define TAILOFF (2 * (size_t)QD + 2 * (size_t)PP)  // 83886080

// zigzag for runtime indexing (constant AS, L1-cached)
__constant__ int c_zz[64] = {
    0,1,8,16,9,2,3,10,17,24,32,25,18,11,4,5,12,19,26,33,40,48,41,34,27,20,13,6,
    7,14,21,28,35,42,49,56,57,50,43,36,29,22,15,23,30,37,44,51,58,59,52,45,38,31,
    39,46,53,60,61,54,47,55,62,63};

struct QArg { float Cf[64]; double rqY[64]; double rqC[64]; };

__device__ __forceinline__ double qf_from_rank(double r) {
    double q = rint(2.0 + r * 48.0 + 0.0);
    return fmin(fmax(q, 2.0), 50.0);
}
__device__ __forceinline__ double scale_from_qf(double qf) {
    double s = (qf < 50.0) ? (5000.0 / qf) : (200.0 - 2.0 * qf);
    return rint(s) / 100.0;
}

// Rounded YCbCr for 16 consecutive px of one row; identical fp64 rint math to prior rounds.
__device__ __forceinline__ void ycc16(const float* __restrict__ src, int p0,
                                      int* y, int* cb, int* cr) {
    float px[48];
    const float4* s4 = (const float4*)(src + (size_t)p0 * 3);
    #pragma unroll
    for (int k = 0; k < 12; ++k) ((float4*)px)[k] = s4[k];
    #pragma unroll
    for (int k = 0; k < 16; ++k) {
        double R = px[3 * k], G = px[3 * k + 1], Bv = px[3 * k + 2];
        y[k]  = (int)(rint(R * (double)0.299f     + G * (double)0.587f     + Bv * (double)0.114f)             - 128.0);
        cb[k] = (int)(rint(R * (double)-0.168736f + G * (double)-0.331264f + Bv * (double)0.5f       + 128.0) - 128.0);
        cr[k] = (int)(rint(R * (double)0.5f       + G * (double)-0.418688f + Bv * (double)-0.081312f + 128.0) - 128.0);
    }
}

// Energy via Parseval + cache rounded YCC planes (int16) for k_quant.
// planes layout: [b][ch][512 rows][512 cols] int16, plane stride 1<<18 shorts.
__global__ __launch_bounds__(256, 4) void k_energy(const float* __restrict__ rgb,
                                                   short* __restrict__ planes,
                                                   double* __restrict__ ey,
                                                   double* __restrict__ ec) {
    __shared__ int4 part[3][8][32];
    __shared__ double ecomb[2][64];
    int b = blockIdx.x >> 6, i = blockIdx.x & 63, t = threadIdx.x;
    const float* src = rgb + (size_t)(b * HH + i * 8) * WW * 3;
    {
        int y[16], cb[16], cr[16];
        ycc16(src, t * 16, y, cb, cr);
        int s[3][2] = {{0,0},{0,0},{0,0}}, s2[3][2] = {{0,0},{0,0},{0,0}};
        alignas(16) short yb[16], cbb[16], crb[16];
        #pragma unroll
        for (int k = 0; k < 16; ++k) {
            int h = k >> 3;
            s[0][h] += y[k];  s2[0][h] += y[k] * y[k];
            s[1][h] += cb[k]; s2[1][h] += cb[k] * cb[k];
            s[2][h] += cr[k]; s2[2][h] += cr[k] * cr[k];
            yb[k] = (short)y[k]; cbb[k] = (short)cb[k]; crb[k] = (short)cr[k];
        }
        // strip-linear == row-major global rows: offset (i*8)*512 + t*16 shorts
        size_t soff = (size_t)i * 4096 + (size_t)t * 16;
        short* d0 = planes + (((size_t)(b * 3 + 0)) << 18) + soff;
        short* d1 = planes + (((size_t)(b * 3 + 1)) << 18) + soff;
        short* d2 = planes + (((size_t)(b * 3 + 2)) << 18) + soff;
        ((int4*)d0)[0] = ((int4*)yb)[0];  ((int4*)d0)[1] = ((int4*)yb)[1];
        ((int4*)d1)[0] = ((int4*)cbb)[0]; ((int4*)d1)[1] = ((int4*)cbb)[1];
        ((int4*)d2)[0] = ((int4*)crb)[0]; ((int4*)d2)[1] = ((int4*)crb)[1];
        int r0 = t >> 5, c = t & 31;
        #pragma unroll
        for (int ch = 0; ch < 3; ++ch)
            part[ch][r0][c] = make_int4(s[ch][0], s2[ch][0], s[ch][1], s2[ch][1]);
    }
    __syncthreads();
    int ch = t >> 6, j = t & 63;
    if (ch < 3) {
        int S = 0, S2 = 0;
        #pragma unroll
        for (int r = 0; r < 8; ++r) {
            const int2* p = (const int2*)&part[ch][r][j >> 1];
            int2 v = p[j & 1];
            S += v.x; S2 += v.y;
        }
        double e = log1p((double)S2 - (double)S * (double)S * (1.0 / 64.0) + 1e-6);
        if (ch == 0) ey[b * NB + i * 64 + j] = e;
        else ecomb[ch - 1][j] = e;
    }
    __syncthreads();
    if (t < 64) ec[b * NB + i * 64 + t] = 0.5 * (ecomb[0][t] + ecomb[1][t]);
}

// Fused quant: per-WG redundant minmax (bit-exact, fmin/fmax order-independent),
// DCT+quant from cached int16 planes, neighbor block (i-1,63) recomputed by
// threads 192-194 through the SAME code path (bit-identical) so the j==0
// zigzag-delta is resolved in-kernel. Replaces k_minmax + k_quant + k_fix.
__global__ __launch_bounds__(256, 4) void k_quant(const short* __restrict__ planes,
                                                  QArg A,
                                                  const double* __restrict__ ey,
                                                  const double* __restrict__ ec,
                                                  float* __restrict__ out) {
    __shared__ __align__(16) char lds[27584];
    short* sqA = (short*)lds;                    // [195][68] shorts, 26520 B
    float4* qsc = (float4*)(lds + 26560);        // [64] {qy,qc,sy,sc}
    double* red = (double*)lds;                  // overlay scratch, 8192 B (dead before sqA writes)

    int b = blockIdx.x >> 6, i = blockIdx.x & 63, t = threadIdx.x;

    // ---- in-WG minmax over image b's 4096 block energies ----
    double mny = 1e300, mxy = -1e300, mnc = 1e300, mxc = -1e300;
    const double* eyb = ey + (size_t)b * NB;
    const double* ecb = ec + (size_t)b * NB;
    for (int n = t; n < NB; n += 256) {
        double vy = eyb[n], vc = ecb[n];
        mny = fmin(mny, vy); mxy = fmax(mxy, vy);
        mnc = fmin(mnc, vc); mxc = fmax(mxc, vc);
    }
    red[t] = mny; red[256 + t] = mxy; red[512 + t] = mnc; red[768 + t] = mxc;
    __syncthreads();
    for (int off = 128; off > 0; off >>= 1) {
        if (t < off) {
            red[t]       = fmin(red[t],       red[t + off]);
            red[256 + t] = fmax(red[256 + t], red[256 + t + off]);
            red[512 + t] = fmin(red[512 + t], red[512 + t + off]);
            red[768 + t] = fmax(red[768 + t], red[768 + t + off]);
        }
        __syncthreads();
    }
    mny = red[0]; mxy = red[256]; mnc = red[512]; mxc = red[768];
    __syncthreads();                             // red scratch dead

    if (i == 0 && t == 0) {
        double ry = (mxy - mny) / (mxy - mny + 1e-6);
        double rc = (mxc - mnc) / (mxc - mnc + 1e-6);
        float* tail = out + TAILOFF;
        tail[b]      = (float)qf_from_rank(0.0);
        tail[32 + b] = (float)qf_from_rank(ry);
        tail[64 + b] = (float)qf_from_rank(0.0);
        tail[96 + b] = (float)qf_from_rank(rc);
    }

    // ---- virtual-block mapping: t<192 -> (ch, j, strip i); t in [192,195) ->
    //      neighbor block (ch, 63, strip i-1) for the j==0 delta ----
    int ch = 0, j = 0, ii = i, row = 0;
    bool act = false, zero = false;
    if (t < 192)      { ch = t >> 6;  j = t & 63; row = (ch * 64 + j) * 68; act = true; }
    else if (t < 195) { ch = t - 192; j = 63; ii = i - 1; row = (192 + ch) * 68;
                        act = true; zero = (i == 0); }

    if (act && zero) {
        // first strip: reference keeps block 0 as-is (prev == 0)
        #pragma unroll
        for (int u = 0; u < 16; ++u) ((long long*)&sqA[row])[u] = 0LL;
    }
    if (act && !zero) {
        // decision math (fp64, identical to prior rounds)
        int gt = b * NB + ii * 64 + j;
        double eyv = ey[gt], ecv = ec[gt];
        double ry = (eyv - mny) / (mxy - mny + 1e-6);
        double rc = (ecv - mnc) / (mxc - mnc + 1e-6);
        double qy = qf_from_rank(ry), qc = qf_from_rank(rc);
        double sy = scale_from_qf(qy), sc = scale_from_qf(qc);
        if (t < 64) qsc[j] = make_float4((float)qy, (float)qc, (float)sy, (float)sc);
        // fp32 DCT row pass, straight from global int16 planes (coalesced)
        const short* pl = planes + (((size_t)(b * 3 + ch)) << 18)
                        + (size_t)ii * 4096 + (size_t)j * 8;
        float U[8][8];
        #pragma unroll
        for (int r = 0; r < 8; ++r) {
            alignas(16) short xs[8];
            *(int4*)xs = *(const int4*)(pl + (size_t)r * 512);
            float xr[8];
            #pragma unroll
            for (int s = 0; s < 8; ++s) xr[s] = (float)xs[s];
            #pragma unroll
            for (int v = 0; v < 8; ++v) {
                float u = 0.0f;
                #pragma unroll
                for (int s = 0; s < 8; ++s) u += xr[s] * A.Cf[v * 8 + s];
                U[r][v] = u;
            }
        }
        double rinv = 1.0 / ((ch == 0) ? sy : sc);
        const double* rqt = (ch == 0) ? A.rqY : A.rqC;
        #pragma unroll
        for (int u = 0; u < 8; ++u) {
            alignas(8) short srow[8];
            #pragma unroll
            for (int v = 0; v < 8; ++v) {
                float dq = (float)rint([&]{
                    float d = 0.0f;
                    #pragma unroll
                    for (int r = 0; r < 8; ++r) d += A.Cf[u * 8 + r] * U[r][v];
                    return (double)d * (rqt[u * 8 + v] * rinv);
                }());
                srow[v] = (short)(int)dq;
            }
            ((long long*)&sqA[row + u * 8])[0] = ((long long*)srow)[0];
            ((long long*)&sqA[row + u * 8 + 4])[0] = ((long long*)srow)[1];
        }
    }
    __syncthreads();

    size_t obase = ((size_t)b * 3 * NB + (size_t)i * 64) * 64;
    int k4 = (t & 15) * 4;  // (it*256) % 16 == 0, so k4 is it-invariant
    // writer A: qdct, contiguous float4 stream
    #pragma unroll
    for (int it = 0; it < 12; ++it) {
        int m = it * 256 + t;
        int mch = m >> 10, f = m & 1023;
        int mj = f >> 4;
        alignas(8) short s4[4];
        *(long long*)s4 = *(const long long*)&sqA[(mch * 64 + mj) * 68 + k4];
        float4 v = make_float4((float)s4[0], (float)s4[1], (float)s4[2], (float)s4[3]);
        *(float4*)(out + obase + (size_t)mch * NB * 64 + (size_t)mj * 64 + k4) = v;
    }
    // writer B: blocks = log2(|zigzag-delta|+1); prev block is j-1 in this tile,
    // or the recomputed neighbor row (192+mch) when mj==0.
    int zk0 = c_zz[k4], zk1 = c_zz[k4 + 1], zk2 = c_zz[k4 + 2], zk3 = c_zz[k4 + 3];
    #pragma unroll
    for (int it = 0; it < 12; ++it) {
        int m = it * 256 + t;
        int mch = m >> 10, f = m & 1023;
        int mj = f >> 4;
        int rowc = (mch * 64 + mj) * 68;
        int rowp = mj ? (rowc - 68) : (192 + mch) * 68;
        float d0 = (float)(sqA[rowc + zk0] - sqA[rowp + zk0]);
        float d1 = (float)(sqA[rowc + zk1] - sqA[rowp + zk1]);
        float d2 = (float)(sqA[rowc + zk2] - sqA[rowp + zk2]);
        float d3 = (float)(sqA[rowc + zk3] - sqA[rowp + zk3]);
        float4 v = make_float4(log2f(fabsf(d0) + 1.0f),
                               log2f(fabsf(d1) + 1.0f),
                               log2f(fabsf(d2) + 1.0f),
                               log2f(fabsf(d3) + 1.0f));
        *(float4*)(out + QD + obase + (size_t)mch * NB * 64 + (size_t)mj * 64 + k4) = v;
    }
    // writer C: pixel maps, contiguous float4 rows
    {
        float4 qs = qsc[t >> 2];
        float4 qv = make_float4(qs.x, qs.y, qs.x, qs.y);
        float4 sv = make_float4(qs.z, qs.w, qs.z, qs.w);
        float2* mq = (float2*)(out + 2 * (size_t)QD);
        float2* ms = (float2*)(out + 2 * (size_t)QD + PP);
        #pragma unroll
        for (int rr = 0; rr < 8; ++rr) {
            size_t P = ((size_t)(b * HH + i * 8 + rr)) * WW;
            ((float4*)(mq + P))[t] = qv;
            ((float4*)(ms + P))[t] = sv;
        }
    }
}

extern "C" void kernel_launch(void* const* d_in, const int* in_sizes, int n_in,
                              void* d_out, int out_size, void* d_ws, size_t ws_size,
                              hipStream_t stream) {
    const float* rgb = (const float*)d_in[0];
    float* out = (float*)d_out;
    double* ws = (double*)d_ws;
    double* ey = ws;                               // 1 MB
    double* ec = ws + (size_t)BB * NB;             // 1 MB
    short* planes = (short*)(ws + 2 * (size_t)BB * NB);  // 50.3 MB int16 YCC

    static const double YQ[64] = {
        16,11,10,16,24,40,51,61, 12,12,14,19,26,58,60,55, 14,13,16,24,40,57,69,56,
        14,17,22,29,51,87,80,62, 18,22,37,56,68,109,103,77, 24,36,55,64,81,104,113,92,
        49,64,78,87,103,121,120,101, 72,92,95,98,112,100,103,99};
    static const double CQ[64] = {
        17,18,24,47,99,99,99,99, 18,21,26,66,99,99,99,99, 24,26,56,99,99,99,99,99,
        47,66,99,99,99,99,99,99, 99,99,99,99,99,99,99,99, 99,99,99,99,99,99,99,99,
        99,99,99,99,99,99,99,99, 99,99,99,99,99,99,99,99};

    QArg qa;
    for (int k = 0; k < 8; ++k)
        for (int n = 0; n < 8; ++n) {
            double v = 0.5 * cos((2.0 * n + 1.0) * (double)k * M_PI / 16.0);
            if (k == 0) v *= 0.70710678118654752440;
            qa.Cf[k * 8 + n] = (float)v;          // reference casts DCT_M to fp32
        }
    for (int k = 0; k < 64; ++k) { qa.rqY[k] = 1.0 / YQ[k]; qa.rqC[k] = 1.0 / CQ[k]; }

    dim3 blk(256);
    k_energy<<<BB * 64, blk, 0, stream>>>(rgb, planes, ey, ec);
    k_quant<<<BB * 64, blk, 0, stream>>>(planes, qa, ey, ec, out);
}

// Round 4
// 428.014 us; speedup vs baseline: 1.0396x; 1.0396x over previous
//
#include <hip/hip_runtime.h>
#include <math.h>

#define BB 32
#define HH 512
#define WW 512
#define NB 4096                      // 64*64 blocks per image
#define QD 25165824                  // 32*3*4096*64  (qdct elements)
#define PP 16777216                  // 32*512*512*2  (enc_qf elements)
#define TAILOFF (2 * (size_t)QD + 2 * (size_t)PP)  // 83886080

// zigzag for runtime indexing (constant AS, L1-cached)
__constant__ int c_zz[64] = {
    0,1,8,16,9,2,3,10,17,24,32,25,18,11,4,5,12,19,26,33,40,48,41,34,27,20,13,6,
    7,14,21,28,35,42,49,56,57,50,43,36,29,22,15,23,30,37,44,51,58,59,52,45,38,31,
    39,46,53,60,61,54,47,55,62,63};

struct QArg { float Cf[64]; double rqY[64]; double rqC[64]; };

__device__ __forceinline__ double qf_from_rank(double r) {
    double q = rint(2.0 + r * 48.0 + 0.0);
    return fmin(fmax(q, 2.0), 50.0);
}
__device__ __forceinline__ double scale_from_qf(double qf) {
    double s = (qf < 50.0) ? (5000.0 / qf) : (200.0 - 2.0 * qf);
    return rint(s) / 100.0;
}

// Rounded YCbCr for 16 consecutive px of one row; identical fp64 rint math to prior rounds.
__device__ __forceinline__ void ycc16(const float* __restrict__ src, int p0,
                                      int* y, int* cb, int* cr) {
    float px[48];
    const float4* s4 = (const float4*)(src + (size_t)p0 * 3);
    #pragma unroll
    for (int k = 0; k < 12; ++k) ((float4*)px)[k] = s4[k];
    #pragma unroll
    for (int k = 0; k < 16; ++k) {
        double R = px[3 * k], G = px[3 * k + 1], Bv = px[3 * k + 2];
        y[k]  = (int)(rint(R * (double)0.299f     + G * (double)0.587f     + Bv * (double)0.114f)             - 128.0);
        cb[k] = (int)(rint(R * (double)-0.168736f + G * (double)-0.331264f + Bv * (double)0.5f       + 128.0) - 128.0);
        cr[k] = (int)(rint(R * (double)0.5f       + G * (double)-0.418688f + Bv * (double)-0.081312f + 128.0) - 128.0);
    }
}

// Energy via Parseval + cache rounded YCC planes (int8: all channels fit
// [-128,127] exactly, lossless) for k_quant.
// planes layout: [b][ch][512 rows][512 cols] int8, plane stride 1<<18 bytes.
__global__ __launch_bounds__(256, 4) void k_energy(const float* __restrict__ rgb,
                                                   signed char* __restrict__ planes,
                                                   double* __restrict__ ey,
                                                   double* __restrict__ ec) {
    __shared__ int4 part[3][8][32];
    __shared__ double ecomb[2][64];
    int b = blockIdx.x >> 6, i = blockIdx.x & 63, t = threadIdx.x;
    const float* src = rgb + (size_t)(b * HH + i * 8) * WW * 3;
    {
        int y[16], cb[16], cr[16];
        ycc16(src, t * 16, y, cb, cr);
        int s[3][2] = {{0,0},{0,0},{0,0}}, s2[3][2] = {{0,0},{0,0},{0,0}};
        alignas(16) signed char yb[16], cbb[16], crb[16];
        #pragma unroll
        for (int k = 0; k < 16; ++k) {
            int h = k >> 3;
            s[0][h] += y[k];  s2[0][h] += y[k] * y[k];
            s[1][h] += cb[k]; s2[1][h] += cb[k] * cb[k];
            s[2][h] += cr[k]; s2[2][h] += cr[k] * cr[k];
            yb[k] = (signed char)y[k]; cbb[k] = (signed char)cb[k]; crb[k] = (signed char)cr[k];
        }
        // strip-linear == row-major global rows: offset (i*8)*512 + t*16 bytes
        size_t soff = (size_t)i * 4096 + (size_t)t * 16;
        signed char* d0 = planes + (((size_t)(b * 3 + 0)) << 18) + soff;
        signed char* d1 = planes + (((size_t)(b * 3 + 1)) << 18) + soff;
        signed char* d2 = planes + (((size_t)(b * 3 + 2)) << 18) + soff;
        *(int4*)d0 = *(int4*)yb;
        *(int4*)d1 = *(int4*)cbb;
        *(int4*)d2 = *(int4*)crb;
        int r0 = t >> 5, c = t & 31;
        #pragma unroll
        for (int ch = 0; ch < 3; ++ch)
            part[ch][r0][c] = make_int4(s[ch][0], s2[ch][0], s[ch][1], s2[ch][1]);
    }
    __syncthreads();
    int ch = t >> 6, j = t & 63;
    if (ch < 3) {
        int S = 0, S2 = 0;
        #pragma unroll
        for (int r = 0; r < 8; ++r) {
            const int2* p = (const int2*)&part[ch][r][j >> 1];
            int2 v = p[j & 1];
            S += v.x; S2 += v.y;
        }
        double e = log1p((double)S2 - (double)S * (double)S * (1.0 / 64.0) + 1e-6);
        if (ch == 0) ey[b * NB + i * 64 + j] = e;
        else ecomb[ch - 1][j] = e;
    }
    __syncthreads();
    if (t < 64) ec[b * NB + i * 64 + t] = 0.5 * (ecomb[0][t] + ecomb[1][t]);
}

__global__ __launch_bounds__(256) void k_minmax(const double* __restrict__ ey,
                                                const double* __restrict__ ec,
                                                double* __restrict__ mm,
                                                float* __restrict__ out_tail) {
    __shared__ double s0[256], s1[256], s2[256], s3[256];
    int b = blockIdx.x, tid = threadIdx.x;
    double mny = 1e300, mxy = -1e300, mnc = 1e300, mxc = -1e300;
    for (int n = tid; n < NB; n += 256) {
        double vy = ey[b * NB + n], vc = ec[b * NB + n];
        mny = fmin(mny, vy); mxy = fmax(mxy, vy);
        mnc = fmin(mnc, vc); mxc = fmax(mxc, vc);
    }
    s0[tid] = mny; s1[tid] = mxy; s2[tid] = mnc; s3[tid] = mxc;
    __syncthreads();
    for (int off = 128; off > 0; off >>= 1) {
        if (tid < off) {
            s0[tid] = fmin(s0[tid], s0[tid + off]);
            s1[tid] = fmax(s1[tid], s1[tid + off]);
            s2[tid] = fmin(s2[tid], s2[tid + off]);
            s3[tid] = fmax(s3[tid], s3[tid + off]);
        }
        __syncthreads();
    }
    if (tid == 0) {
        mm[b] = s0[0]; mm[32 + b] = s1[0]; mm[64 + b] = s2[0]; mm[96 + b] = s3[0];
        double ry = (s1[0] - s0[0]) / (s1[0] - s0[0] + 1e-6);
        double rc = (s3[0] - s2[0]) / (s3[0] - s2[0] + 1e-6);
        out_tail[b]      = (float)qf_from_rank(0.0);
        out_tail[32 + b] = (float)qf_from_rank(ry);
        out_tail[64 + b] = (float)qf_from_rank(0.0);
        out_tail[96 + b] = (float)qf_from_rank(rc);
    }
}

// Quant: reads cached int8 YCC planes + precomputed per-image minmax (mm).
// Neighbor block (i-1,63) recomputed by threads 192-194 through the SAME code
// path (bit-identical) so the j==0 zigzag-delta is resolved in-LDS (no k_fix).
__global__ __launch_bounds__(256, 4) void k_quant(const signed char* __restrict__ planes,
                                                  QArg A,
                                                  const double* __restrict__ ey,
                                                  const double* __restrict__ ec,
                                                  const double* __restrict__ mm,
                                                  float* __restrict__ out) {
    __shared__ __align__(16) char lds[27584];
    short* sqA = (short*)lds;                    // [195][68] shorts, 26520 B
    float4* qsc = (float4*)(lds + 26560);        // [64] {qy,qc,sy,sc}

    int b = blockIdx.x >> 6, i = blockIdx.x & 63, t = threadIdx.x;

    // virtual-block mapping: t<192 -> (ch, j, strip i); t in [192,195) ->
    // neighbor block (ch, 63, strip i-1) for the j==0 zigzag-delta
    int ch = 0, j = 0, ii = i, row = 0;
    bool act = false, zero = false;
    if (t < 192)      { ch = t >> 6;  j = t & 63; row = (ch * 64 + j) * 68; act = true; }
    else if (t < 195) { ch = t - 192; j = 63; ii = i - 1; row = (192 + ch) * 68;
                        act = true; zero = (i == 0); }

    if (act && zero) {
        // first strip: reference keeps block 0 as-is (prev == 0)
        #pragma unroll
        for (int u = 0; u < 16; ++u) ((long long*)&sqA[row])[u] = 0LL;
    }
    if (act && !zero) {
        // decision math (fp64, identical to prior rounds)
        int gt = b * NB + ii * 64 + j;
        double eyv = ey[gt], ecv = ec[gt];
        double mny = mm[b], mxy = mm[32 + b], mnc = mm[64 + b], mxc = mm[96 + b];
        double ry = (eyv - mny) / (mxy - mny + 1e-6);
        double rc = (ecv - mnc) / (mxc - mnc + 1e-6);
        double qy = qf_from_rank(ry), qc = qf_from_rank(rc);
        double sy = scale_from_qf(qy), sc = scale_from_qf(qc);
        if (t < 64) qsc[j] = make_float4((float)qy, (float)qc, (float)sy, (float)sc);
        // fp32 DCT row pass, straight from global int8 planes (coalesced)
        const signed char* pl = planes + (((size_t)(b * 3 + ch)) << 18)
                              + (size_t)ii * 4096 + (size_t)j * 8;
        float U[8][8];
        #pragma unroll
        for (int r = 0; r < 8; ++r) {
            alignas(8) signed char xs[8];
            *(long long*)xs = *(const long long*)(pl + (size_t)r * 512);
            float xr[8];
            #pragma unroll
            for (int s = 0; s < 8; ++s) xr[s] = (float)xs[s];
            #pragma unroll
            for (int v = 0; v < 8; ++v) {
                float u = 0.0f;
                #pragma unroll
                for (int s = 0; s < 8; ++s) u += xr[s] * A.Cf[v * 8 + s];
                U[r][v] = u;
            }
        }
        double rinv = 1.0 / ((ch == 0) ? sy : sc);
        const double* rqt = (ch == 0) ? A.rqY : A.rqC;
        #pragma unroll
        for (int u = 0; u < 8; ++u) {
            alignas(8) short srow[8];
            #pragma unroll
            for (int v = 0; v < 8; ++v) {
                float dq = (float)rint([&]{
                    float d = 0.0f;
                    #pragma unroll
                    for (int r = 0; r < 8; ++r) d += A.Cf[u * 8 + r] * U[r][v];
                    return (double)d * (rqt[u * 8 + v] * rinv);
                }());
                srow[v] = (short)(int)dq;
            }
            ((long long*)&sqA[row + u * 8])[0] = ((long long*)srow)[0];
            ((long long*)&sqA[row + u * 8 + 4])[0] = ((long long*)srow)[1];
        }
    }
    __syncthreads();

    size_t obase = ((size_t)b * 3 * NB + (size_t)i * 64) * 64;
    int k4 = (t & 15) * 4;  // (it*256) % 16 == 0, so k4 is it-invariant
    // writer A: qdct, contiguous float4 stream
    #pragma unroll
    for (int it = 0; it < 12; ++it) {
        int m = it * 256 + t;
        int mch = m >> 10, f = m & 1023;
        int mj = f >> 4;
        alignas(8) short s4[4];
        *(long long*)s4 = *(const long long*)&sqA[(mch * 64 + mj) * 68 + k4];
        float4 v = make_float4((float)s4[0], (float)s4[1], (float)s4[2], (float)s4[3]);
        *(float4*)(out + obase + (size_t)mch * NB * 64 + (size_t)mj * 64 + k4) = v;
    }
    // writer B: blocks = log2(|zigzag-delta|+1); prev block is j-1 in this tile,
    // or the recomputed neighbor row (192+mch) when mj==0.
    int zk0 = c_zz[k4], zk1 = c_zz[k4 + 1], zk2 = c_zz[k4 + 2], zk3 = c_zz[k4 + 3];
    #pragma unroll
    for (int it = 0; it < 12; ++it) {
        int m = it * 256 + t;
        int mch = m >> 10, f = m & 1023;
        int mj = f >> 4;
        int rowc = (mch * 64 + mj) * 68;
        int rowp = mj ? (rowc - 68) : (192 + mch) * 68;
        float d0 = (float)(sqA[rowc + zk0] - sqA[rowp + zk0]);
        float d1 = (float)(sqA[rowc + zk1] - sqA[rowp + zk1]);
        float d2 = (float)(sqA[rowc + zk2] - sqA[rowp + zk2]);
        float d3 = (float)(sqA[rowc + zk3] - sqA[rowp + zk3]);
        float4 v = make_float4(log2f(fabsf(d0) + 1.0f),
                               log2f(fabsf(d1) + 1.0f),
                               log2f(fabsf(d2) + 1.0f),
                               log2f(fabsf(d3) + 1.0f));
        *(float4*)(out + QD + obase + (size_t)mch * NB * 64 + (size_t)mj * 64 + k4) = v;
    }
    // writer C: pixel maps, contiguous float4 rows
    {
        float4 qs = qsc[t >> 2];
        float4 qv = make_float4(qs.x, qs.y, qs.x, qs.y);
        float4 sv = make_float4(qs.z, qs.w, qs.z, qs.w);
        float2* mq = (float2*)(out + 2 * (size_t)QD);
        float2* ms = (float2*)(out + 2 * (size_t)QD + PP);
        #pragma unroll
        for (int rr = 0; rr < 8; ++rr) {
            size_t P = ((size_t)(b * HH + i * 8 + rr)) * WW;
            ((float4*)(mq + P))[t] = qv;
            ((float4*)(ms + P))[t] = sv;
        }
    }
}

extern "C" void kernel_launch(void* const* d_in, const int* in_sizes, int n_in,
                              void* d_out, int out_size, void* d_ws, size_t ws_size,
                              hipStream_t stream) {
    const float* rgb = (const float*)d_in[0];
    float* out = (float*)d_out;
    double* ws = (double*)d_ws;
    double* ey = ws;                               // 1 MB
    double* ec = ws + (size_t)BB * NB;             // 1 MB
    double* mm = ws + 2 * (size_t)BB * NB;         // 1 KB (128 doubles)
    signed char* planes = (signed char*)(ws + 2 * (size_t)BB * NB + 128);  // 25.2 MB int8 YCC

    static const double YQ[64] = {
        16,11,10,16,24,40,51,61, 12,12,14,19,26,58,60,55, 14,13,16,24,40,57,69,56,
        14,17,22,29,51,87,80,62, 18,22,37,56,68,109,103,77, 24,36,55,64,81,104,113,92,
        49,64,78,87,103,121,120,101, 72,92,95,98,112,100,103,99};
    static const double CQ[64] = {
        17,18,24,47,99,99,99,99, 18,21,26,66,99,99,99,99, 24,26,56,99,99,99,99,99,
        47,66,99,99,99,99,99,99, 99,99,99,99,99,99,99,99, 99,99,99,99,99,99,99,99,
        99,99,99,99,99,99,99,99, 99,99,99,99,99,99,99,99};

    QArg qa;
    for (int k = 0; k < 8; ++k)
        for (int n = 0; n < 8; ++n) {
            double v = 0.5 * cos((2.0 * n + 1.0) * (double)k * M_PI / 16.0);
            if (k == 0) v *= 0.70710678118654752440;
            qa.Cf[k * 8 + n] = (float)v;          // reference casts DCT_M to fp32
        }
    for (int k = 0; k < 64; ++k) { qa.rqY[k] = 1.0 / YQ[k]; qa.rqC[k] = 1.0 / CQ[k]; }

    dim3 blk(256);
    k_energy<<<BB * 64, blk, 0, stream>>>(rgb, planes, ey, ec);
    k_minmax<<<BB, blk, 0, stream>>>(ey, ec, mm, out + TAILOFF);
    k_quant<<<BB * 64, blk, 0, stream>>>(planes, qa, ey, ec, mm, out);
}